// Round 12
// baseline (191.499 us; speedup 1.0000x reference)
//
#include <hip/hip_runtime.h>
#include <hip/hip_bf16.h>

#define NPTS   2048
#define IDIM   16
#define HDIM   32
#define CUTSN  8
#define EPSV   1e-5f
#define PSCALE 0.07856742013183862f   /* 1/(sqrt(2)*9) */
#define ICH    4                      /* i-rows per block chunk */
#define IPK    48                     /* floats per ipack row (192B aligned) */

typedef __bf16 bf16x8 __attribute__((ext_vector_type(8)));
typedef float  f32x16 __attribute__((ext_vector_type(16)));

__device__ __forceinline__ float leaky(float x) { return x >= 0.f ? x : 0.2f * x; }

/* ------- two-layer MLP (per-row) + GroupNorm partial sums (+ipack/zero) -------
 * 32 blocks x 64 threads (one wave), one row per thread. partials (256 floats):
 * [g*32 + block] = group sums, [128 + g*32 + block] = group sumsq.
 * ipack row (40 used of 48):
 *   c=0..7 : {Mx,My,Mz,bias'}  M_c = A1_c @ nuv_i, bias' = B1_c - M_c.(s p_i)
 *   [32..35]: {-2 s p_i, q_i}   q_i = |s p_i|^2
 *   [36..39]: {n_i, 0}                                              */
template <int K>
__global__ __launch_bounds__(64) void net2_kernel(
    const float* __restrict__ xin,
    const float* __restrict__ W1, const float* __restrict__ b1,
    const float* __restrict__ W2, const float* __restrict__ b2,
    float* __restrict__ out, float* __restrict__ partials,
    float* __restrict__ zbuf,
    const float* __restrict__ points, const float* __restrict__ nuv,
    const float* __restrict__ A1, const float* __restrict__ B1,
    float* __restrict__ ipack)
{
    const int t = threadIdx.x;
    const int i = blockIdx.x * 64 + t;
    if (zbuf) {
#pragma unroll
        for (int e = 0; e < 8; ++e)
            *(float4*)&zbuf[i * HDIM + e * 4] = make_float4(0.f, 0.f, 0.f, 0.f);
    }
    if (ipack) {
        float* ip = ipack + i * IPK;
        const float spx = points[i * 3 + 0] * PSCALE;
        const float spy = points[i * 3 + 1] * PSCALE;
        const float spz = points[i * 3 + 2] * PSCALE;
#pragma unroll
        for (int c = 0; c < 8; ++c) {
            float m0 = 0.f, m1 = 0.f, m2 = 0.f;
#pragma unroll
            for (int a = 0; a < 3; ++a) {
                const float wA = A1[c * 3 + a];
                m0 = fmaf(wA, nuv[i * 9 + a * 3 + 0], m0);
                m1 = fmaf(wA, nuv[i * 9 + a * 3 + 1], m1);
                m2 = fmaf(wA, nuv[i * 9 + a * 3 + 2], m2);
            }
            const float bp = B1[c] - (m0 * spx + m1 * spy + m2 * spz);
            *(float4*)&ip[c * 4] = make_float4(m0, m1, m2, bp);
        }
        *(float4*)&ip[32] = make_float4(-2.f * spx, -2.f * spy, -2.f * spz,
                                        spx * spx + spy * spy + spz * spz);
        *(float4*)&ip[36] = make_float4(nuv[i * 9 + 0], nuv[i * 9 + 1],
                                        nuv[i * 9 + 2], 0.f);
        *(float4*)&ip[40] = make_float4(0.f, 0.f, 0.f, 0.f);
        *(float4*)&ip[44] = make_float4(0.f, 0.f, 0.f, 0.f);
    }

    float x[K];
#pragma unroll
    for (int k = 0; k < K; ++k) x[k] = xin[i * K + k];

    float y[HDIM];
#pragma unroll
    for (int h = 0; h < HDIM; ++h) {
        float v = b1[h];
#pragma unroll
        for (int k = 0; k < K; ++k) v = fmaf(x[k], W1[h * K + k], v);
        y[h] = leaky(v);
    }
    float ps[4]  = {0.f, 0.f, 0.f, 0.f};
    float pss[4] = {0.f, 0.f, 0.f, 0.f};
#pragma unroll
    for (int h = 0; h < HDIM; ++h) {
        float v = b2[h];
#pragma unroll
        for (int k = 0; k < HDIM; ++k) v = fmaf(y[k], W2[h * HDIM + k], v);
        v = leaky(v);
        out[i * HDIM + h] = v;
        const int g = h >> 3;                 /* compile-time after unroll */
        ps[g] += v; pss[g] = fmaf(v, v, pss[g]);
    }
#pragma unroll
    for (int off = 32; off; off >>= 1) {
#pragma unroll
        for (int g = 0; g < 4; ++g) {
            ps[g]  += __shfl_down(ps[g],  off, 64);
            pss[g] += __shfl_down(pss[g], off, 64);
        }
    }
    if (t == 0) {
#pragma unroll
        for (int g = 0; g < 4; ++g) {
            partials[g * 32 + blockIdx.x]       = ps[g];
            partials[128 + g * 32 + blockIdx.x] = pss[g];
        }
    }
}

/* ------- GroupNorm apply (final output): reduces block-partials inline ------- */
__global__ __launch_bounds__(256) void gn_apply_kernel(
    const float* __restrict__ x, const float* __restrict__ partials,
    const float* __restrict__ gw, const float* __restrict__ gb,
    float* __restrict__ out)
{
    const int idx = blockIdx.x * 256 + threadIdx.x;   /* < NPTS*HDIM */
    const int c = idx & (HDIM - 1);
    const int g = c >> 3;
    float s = 0.f, q = 0.f;
#pragma unroll
    for (int b = 0; b < 32; ++b) {
        s += partials[g * 32 + b];
        q += partials[128 + g * 32 + b];
    }
    const float inv = 1.f / (8.f * NPTS);
    const float mu = s * inv;
    const float rs = rsqrtf(q * inv - mu * mu + EPSV);
    out[idx] = fmaf((x[idx] - mu) * rs, gw[c], gb[c]);
}

/* =================== N^2 pairwise via MFMA, two j-tiles per wave ============
 * grid (4, 512): x -> 512-j group (8 waves x 64 j), y -> 4-i chunk.
 * Each wave owns TWO 32-j tiles (A,B) and loops the chunk's 4 i's, 2-deep
 * pipelined on the i-pack s_loads. r10-proven structure (46.4 us); r11's
 * geometry-MFMA restructure regressed (serial MFMA->VALU->MFMA chain,
 * marshalling ~= savings) and is abandoned. Changes vs r10:
 *  - ICH 8->4: grid 1024->2048 blocks, doubles TLP (r10 occupancy was 35%)
 *  - word-packed afrag select: wv is lane-half-invariant, so build u8/w8
 *    unconditionally and cndmask per 32-bit WORD (4 ops) not per element.
 * Per (i, tile): one v_mfma_f32_32x32x16_bf16, K-pack k=0..7 = w*relu(cut),
 * k=8 = w vs B2[h] bias slot. A-frag row=lane&31, k=8*(lane>>5)+e; D
 * col=lane&31, row=(reg&3)+8*(reg>>2)+4*(lane>>5)  [verified round 6].
 * No sched fences (r9/r10 lesson). Static register indices (rule #20).
 * launch_bounds(512,1) = 256-VGPR cap (spill lessons r2-4). */
__global__ __launch_bounds__(512, 1) void pairwise_kernel(
    const float* __restrict__ points, const float* __restrict__ nuv,
    const float* __restrict__ A2, const float* __restrict__ B2,
    const float* __restrict__ ipack,
    const float* __restrict__ traw, const float* __restrict__ partials,
    const float* __restrict__ gw, const float* __restrict__ gb,
    float* __restrict__ fout)
{
    const int t     = threadIdx.x;
    const int lane  = t & 63;
    const int h     = lane & 31;          /* B/D column; local j within tile */
    const bool kh   = (lane >> 5) != 0;
    const int khalf = lane >> 5;
    const int ibase = blockIdx.y * ICH;
    const int jt0   = blockIdx.x * 512 + (t >> 6) * 64;   /* tile A base */

    __shared__ float sacc[ICH][32];       /* 512 B tile accumulator */
    if (t < ICH * 32) ((float*)sacc)[t] = 0.f;
    __syncthreads();

    /* ---- per-lane j-side for both tiles (loaded once) ---- */
    const int jA = jt0 + h, jB = jt0 + 32 + h;
    const float pjxA = points[jA * 3 + 0] * PSCALE;
    const float pjyA = points[jA * 3 + 1] * PSCALE;
    const float pjzA = points[jA * 3 + 2] * PSCALE;
    const float njxA = nuv[jA * 9 + 0], njyA = nuv[jA * 9 + 1], njzA = nuv[jA * 9 + 2];
    const float qjA  = fmaf(pjxA, pjxA, fmaf(pjyA, pjyA, pjzA * pjzA));
    const float pjxB = points[jB * 3 + 0] * PSCALE;
    const float pjyB = points[jB * 3 + 1] * PSCALE;
    const float pjzB = points[jB * 3 + 2] * PSCALE;
    const float njxB = nuv[jB * 9 + 0], njyB = nuv[jB * 9 + 1], njzB = nuv[jB * 9 + 2];
    const float qjB  = fmaf(pjxB, pjxB, fmaf(pjyB, pjyB, pjzB * pjzB));

    /* ---- constant B fragment: A2e[k][h] (same for both tiles) ---- */
    bf16x8 bfrag;
#pragma unroll
    for (int e = 0; e < 8; ++e) {
        const float bv = (khalf == 0) ? A2[h * 8 + e] : (e == 0 ? B2[h] : 0.f);
        bfrag[e] = (__bf16)bv;
    }

    /* ---- GroupNorm-on-the-fly f registers, 16 per tile ---- */
    const int g4 = h >> 3;
    float s = 0.f, q = 0.f;
#pragma unroll
    for (int b = 0; b < 32; ++b) {
        s += partials[g4 * 32 + b];
        q += partials[128 + g4 * 32 + b];
    }
    const float inv = 1.f / (8.f * NPTS);
    const float mu = s * inv;
    const float rs = rsqrtf(q * inv - mu * mu + EPSV);
    const float alpha = rs * gw[h];
    const float gamma = fmaf(-mu, alpha, gb[h]);
    float fregA[16], fregB[16];
#pragma unroll
    for (int r = 0; r < 16; ++r) {
        const int jr = (r & 3) + 8 * (r >> 2) + 4 * khalf;  /* D row for reg r */
        fregA[r] = fmaf(traw[(jt0 + jr) * HDIM + h],      alpha, gamma);
        fregB[r] = fmaf(traw[(jt0 + 32 + jr) * HDIM + h], alpha, gamma);
    }

    f32x16 czero;
#pragma unroll
    for (int e = 0; e < 16; ++e) czero[e] = 0.f;

    float accv[ICH];
#pragma unroll
    for (int il = 0; il < ICH; ++il) accv[il] = 0.f;

/* load one i's pack into named register buffers (wave-uniform -> s_load) */
#define LOADI(M, G8, G9, il) do {                                             \
        const float4* ip4 = (const float4*)(ipack + (ibase + (il)) * IPK);    \
        M[0] = ip4[0]; M[1] = ip4[1]; M[2] = ip4[2]; M[3] = ip4[3];           \
        M[4] = ip4[4]; M[5] = ip4[5]; M[6] = ip4[6]; M[7] = ip4[7];           \
        G8 = ip4[8]; G9 = ip4[9];                                             \
    } while (0)

/* pack u[8]+window into the A-frag: u8/w8 built unconditionally (wv is the
 * same on both lane halves), then ONE 32-bit-word-level select (4 cndmask) */
#define PACKAF(af, u, wv) do {                                                \
        bf16x8 u8_, w8_;                                                      \
        _Pragma("unroll")                                                     \
        for (int e = 0; e < 8; ++e) u8_[e] = (__bf16)u[e];                    \
        w8_[0] = (__bf16)wv;                                                  \
        _Pragma("unroll")                                                     \
        for (int e = 1; e < 8; ++e) w8_[e] = (__bf16)0.f;                     \
        const uint4 uw_ = *(const uint4*)&u8_;                                \
        const uint4 ww_ = *(const uint4*)&w8_;                                \
        uint4 sel_;                                                           \
        sel_.x = kh ? ww_.x : uw_.x;                                          \
        sel_.y = kh ? ww_.y : uw_.y;                                          \
        sel_.z = kh ? ww_.z : uw_.z;                                          \
        sel_.w = kh ? ww_.w : uw_.w;                                          \
        af = *(const bf16x8*)&sel_;                                           \
    } while (0)

/* one i against BOTH 32-j tiles: two independent geometry/u/MFMA/post chains */
#define BODY2(M, G8, G9, il) do {                                             \
        const float sqA = fmaf(G8.x, pjxA, fmaf(G8.y, pjyA,                   \
                          fmaf(G8.z, pjzA, G8.w))) + qjA;                     \
        const float sqB = fmaf(G8.x, pjxB, fmaf(G8.y, pjyB,                   \
                          fmaf(G8.z, pjzB, G8.w))) + qjB;                     \
        const float dtA = fmaf(G9.x, njxA, fmaf(G9.y, njyA, G9.z * njzA));    \
        const float dtB = fmaf(G9.x, njxB, fmaf(G9.y, njyB, G9.z * njzB));    \
        const float ttA = 2.f - dtA, ttB = 2.f - dtB;                         \
        const float wvA = __expf(-sqA * ttA * ttA);                           \
        const float wvB = __expf(-sqB * ttB * ttB);                           \
        float uA[8], uB[8];                                                   \
        _Pragma("unroll")                                                     \
        for (int c = 0; c < 8; ++c) {                                         \
            uA[c] = wvA * fmaxf(fmaf(M[c].x, pjxA, fmaf(M[c].y, pjyA,         \
                                fmaf(M[c].z, pjzA, M[c].w))), 0.f);           \
            uB[c] = wvB * fmaxf(fmaf(M[c].x, pjxB, fmaf(M[c].y, pjyB,         \
                                fmaf(M[c].z, pjzB, M[c].w))), 0.f);           \
        }                                                                     \
        bf16x8 afA, afB;                                                      \
        PACKAF(afA, uA, wvA);                                                 \
        PACKAF(afB, uB, wvB);                                                 \
        const f32x16 dA = __builtin_amdgcn_mfma_f32_32x32x16_bf16(            \
            afA, bfrag, czero, 0, 0, 0);                                      \
        const f32x16 dB = __builtin_amdgcn_mfma_f32_32x32x16_bf16(            \
            afB, bfrag, czero, 0, 0, 0);                                      \
        float a0 = 0.f, a1 = 0.f, b0 = 0.f, b1 = 0.f;                         \
        _Pragma("unroll")                                                     \
        for (int r = 0; r < 16; r += 2) {                                     \
            a0 = fmaf(fmaxf(dA[r],     0.f), fregA[r],     a0);               \
            a1 = fmaf(fmaxf(dA[r + 1], 0.f), fregA[r + 1], a1);               \
            b0 = fmaf(fmaxf(dB[r],     0.f), fregB[r],     b0);               \
            b1 = fmaf(fmaxf(dB[r + 1], 0.f), fregB[r + 1], b1);               \
        }                                                                     \
        accv[il] = (a0 + a1) + (b0 + b1);                                     \
    } while (0)

    /* ---- 2-deep pipelined i-loop; no fences: let 4 MFMA chains overlap ---- */
    float4 MA[8], MB[8], GA8, GA9, GB8, GB9;
    LOADI(MA, GA8, GA9, 0);
#pragma unroll 1
    for (int ii = 0; ii < ICH; ii += 2) {
        LOADI(MB, GB8, GB9, ii + 1);
        BODY2(MA, GA8, GA9, ii);
        if (ii + 2 < ICH) LOADI(MA, GA8, GA9, ii + 2);
        BODY2(MB, GB8, GB9, ii + 1);
    }
#undef LOADI
#undef BODY2
#undef PACKAF

    /* ---- block-level reduction via LDS atomics (outside the hot loop) ---- */
#pragma unroll
    for (int il = 0; il < ICH; ++il)
        atomicAdd(&sacc[il][h], accv[il]);
    __syncthreads();

    /* ---- flush tile to global (ICH*32 = 128 cells) ---- */
    if (t < ICH * 32) {
        const int il0 = t >> 5, h0 = t & 31;
        atomicAdd(&fout[(ibase + il0) * HDIM + h0], sacc[il0][h0]);
    }
}

extern "C" void kernel_launch(void* const* d_in, const int* in_sizes, int n_in,
                              void* d_out, int out_size, void* d_ws, size_t ws_size,
                              hipStream_t stream)
{
    const float* points   = (const float*)d_in[0];
    const float* nuv      = (const float*)d_in[1];
    const float* features = (const float*)d_in[2];
    const float* W_in1    = (const float*)d_in[3];
    const float* b_in1    = (const float*)d_in[4];
    const float* W_in2    = (const float*)d_in[5];
    const float* b_in2    = (const float*)d_in[6];
    const float* g_in_w   = (const float*)d_in[7];
    const float* g_in_b   = (const float*)d_in[8];
    const float* A1       = (const float*)d_in[9];
    const float* A2       = (const float*)d_in[10];
    const float* W_out1   = (const float*)d_in[11];
    const float* b_out1   = (const float*)d_in[12];
    const float* W_out2   = (const float*)d_in[13];
    const float* b_out2   = (const float*)d_in[14];
    const float* g_out_w  = (const float*)d_in[15];
    const float* g_out_b  = (const float*)d_in[16];
    const float* B1       = (const float*)d_in[17];
    const float* B2       = (const float*)d_in[18];

    float* ws    = (float*)d_ws;
    float* t2a   = ws;               /* N*H raw net_in output */
    float* t2b   = ws + 65536;       /* N*H raw net_out output */
    float* fout  = ws + 131072;      /* N*H pairwise accumulator */
    float* ipack = ws + 196608;      /* N*IPK = 98304 */
    float* part1 = ws + 294912;      /* 256 floats */
    float* part2 = ws + 295168;      /* 256 floats */
    float* out   = (float*)d_out;

    /* net_in (+stats partials, +zero fout, +ipack) */
    net2_kernel<IDIM><<<dim3(NPTS / 64), dim3(64), 0, stream>>>(
        features, W_in1, b_in1, W_in2, b_in2, t2a, part1, fout,
        points, nuv, A1, B1, ipack);

    /* all-pairs interaction (GroupNorm of f applied on the fly) */
    pairwise_kernel<<<dim3(NPTS / 512, NPTS / ICH), dim3(512), 0, stream>>>(
        points, nuv, A2, B2, ipack, t2a, part1, g_in_w, g_in_b, fout);

    /* net_out (+stats partials), then final normalize -> out */
    net2_kernel<HDIM><<<dim3(NPTS / 64), dim3(64), 0, stream>>>(
        fout, W_out1, b_out1, W_out2, b_out2, t2b, part2, nullptr,
        nullptr, nullptr, nullptr, nullptr, nullptr);
    gn_apply_kernel<<<dim3(NPTS * HDIM / 256), dim3(256), 0, stream>>>(
        t2b, part2, g_out_w, g_out_b, out);
}

// Round 14
// 162.033 us; speedup vs baseline: 1.1818x; 1.1818x over previous
//
#include <hip/hip_runtime.h>
#include <hip/hip_bf16.h>

#define NPTS   2048
#define IDIM   16
#define HDIM   32
#define CUTSN  8
#define EPSV   1e-5f
#define PSCALE 0.07856742013183862f   /* 1/(sqrt(2)*9) */
#define ICH    8                      /* i-rows per block chunk */
#define IPK    48                     /* floats per ipack row (192B aligned) */

typedef __bf16 bf16x8 __attribute__((ext_vector_type(8)));
typedef float  f32x16 __attribute__((ext_vector_type(16)));

__device__ __forceinline__ float leaky(float x) { return x >= 0.f ? x : 0.2f * x; }

/* ------- two-layer MLP (per-row) + GroupNorm partial sums (+ipack/zero) -------
 * 32 blocks x 64 threads (one wave), one row per thread. partials (256 floats):
 * [g*32 + block] = group sums, [128 + g*32 + block] = group sumsq.
 * ipack row (40 used of 48):
 *   c=0..7 : {Mx,My,Mz,bias'}  M_c = A1_c @ nuv_i, bias' = B1_c - M_c.(s p_i)
 *   [32..35]: {-2 s p_i, q_i}   q_i = |s p_i|^2
 *   [36..39]: {n_i, 0}                                              */
template <int K>
__global__ __launch_bounds__(64) void net2_kernel(
    const float* __restrict__ xin,
    const float* __restrict__ W1, const float* __restrict__ b1,
    const float* __restrict__ W2, const float* __restrict__ b2,
    float* __restrict__ out, float* __restrict__ partials,
    float* __restrict__ zbuf,
    const float* __restrict__ points, const float* __restrict__ nuv,
    const float* __restrict__ A1, const float* __restrict__ B1,
    float* __restrict__ ipack)
{
    const int t = threadIdx.x;
    const int i = blockIdx.x * 64 + t;
    if (zbuf) {
#pragma unroll
        for (int e = 0; e < 8; ++e)
            *(float4*)&zbuf[i * HDIM + e * 4] = make_float4(0.f, 0.f, 0.f, 0.f);
    }
    if (ipack) {
        float* ip = ipack + i * IPK;
        const float spx = points[i * 3 + 0] * PSCALE;
        const float spy = points[i * 3 + 1] * PSCALE;
        const float spz = points[i * 3 + 2] * PSCALE;
#pragma unroll
        for (int c = 0; c < 8; ++c) {
            float m0 = 0.f, m1 = 0.f, m2 = 0.f;
#pragma unroll
            for (int a = 0; a < 3; ++a) {
                const float wA = A1[c * 3 + a];
                m0 = fmaf(wA, nuv[i * 9 + a * 3 + 0], m0);
                m1 = fmaf(wA, nuv[i * 9 + a * 3 + 1], m1);
                m2 = fmaf(wA, nuv[i * 9 + a * 3 + 2], m2);
            }
            const float bp = B1[c] - (m0 * spx + m1 * spy + m2 * spz);
            *(float4*)&ip[c * 4] = make_float4(m0, m1, m2, bp);
        }
        *(float4*)&ip[32] = make_float4(-2.f * spx, -2.f * spy, -2.f * spz,
                                        spx * spx + spy * spy + spz * spz);
        *(float4*)&ip[36] = make_float4(nuv[i * 9 + 0], nuv[i * 9 + 1],
                                        nuv[i * 9 + 2], 0.f);
        *(float4*)&ip[40] = make_float4(0.f, 0.f, 0.f, 0.f);
        *(float4*)&ip[44] = make_float4(0.f, 0.f, 0.f, 0.f);
    }

    float x[K];
#pragma unroll
    for (int k = 0; k < K; ++k) x[k] = xin[i * K + k];

    float y[HDIM];
#pragma unroll
    for (int h = 0; h < HDIM; ++h) {
        float v = b1[h];
#pragma unroll
        for (int k = 0; k < K; ++k) v = fmaf(x[k], W1[h * K + k], v);
        y[h] = leaky(v);
    }
    float ps[4]  = {0.f, 0.f, 0.f, 0.f};
    float pss[4] = {0.f, 0.f, 0.f, 0.f};
#pragma unroll
    for (int h = 0; h < HDIM; ++h) {
        float v = b2[h];
#pragma unroll
        for (int k = 0; k < HDIM; ++k) v = fmaf(y[k], W2[h * HDIM + k], v);
        v = leaky(v);
        out[i * HDIM + h] = v;
        const int g = h >> 3;                 /* compile-time after unroll */
        ps[g] += v; pss[g] = fmaf(v, v, pss[g]);
    }
#pragma unroll
    for (int off = 32; off; off >>= 1) {
#pragma unroll
        for (int g = 0; g < 4; ++g) {
            ps[g]  += __shfl_down(ps[g],  off, 64);
            pss[g] += __shfl_down(pss[g], off, 64);
        }
    }
    if (t == 0) {
#pragma unroll
        for (int g = 0; g < 4; ++g) {
            partials[g * 32 + blockIdx.x]       = ps[g];
            partials[128 + g * 32 + blockIdx.x] = pss[g];
        }
    }
}

/* ------- GroupNorm apply (final output): reduces block-partials inline ------- */
__global__ __launch_bounds__(256) void gn_apply_kernel(
    const float* __restrict__ x, const float* __restrict__ partials,
    const float* __restrict__ gw, const float* __restrict__ gb,
    float* __restrict__ out)
{
    const int idx = blockIdx.x * 256 + threadIdx.x;   /* < NPTS*HDIM */
    const int c = idx & (HDIM - 1);
    const int g = c >> 3;
    float s = 0.f, q = 0.f;
#pragma unroll
    for (int b = 0; b < 32; ++b) {
        s += partials[g * 32 + b];
        q += partials[128 + g * 32 + b];
    }
    const float inv = 1.f / (8.f * NPTS);
    const float mu = s * inv;
    const float rs = rsqrtf(q * inv - mu * mu + EPSV);
    out[idx] = fmaf((x[idx] - mu) * rs, gw[c], gb[c]);
}

/* =================== N^2 pairwise via MFMA, two j-tiles per wave ============
 * grid (4, 256): x -> 512-j group (8 waves x 64 j), y -> 8-i chunk.
 * r10-proven structure (46.4 us best) + ONE change: khalf-split u-chain.
 * r10 computed identical u[8] on lanes l and l+32 (the A-frag only takes u
 * from khalf0 and w from khalf1) - pure duplication. Now each lane computes
 * ONE u-chain for its own half's tile (khalf0 -> tile A, khalf1 -> tile B)
 * using own-half pj; both windows still computed per-lane (keeps the loop
 * free of DS/shfl ops). Tile A uses the r10 B-frag (A2 at k0-7, B2 bias at
 * k8); tile B uses the khalf-MIRRORED B-frag (bias at k0, A2 at k8-15) -
 * mirrored-frag correctness verified in r11 (absmax 0.03125).
 * Per (i, tile): one v_mfma_f32_32x32x16_bf16. A-frag row=lane&31,
 * k=8*(lane>>5)+e; D col=lane&31, row=(reg&3)+8*(reg>>2)+4*(lane>>5)  [r6].
 * No sched fences (r9/r10). Static register indices (rule #20). No uint4
 * punning (r12 regression: LDS temporaries + bank conflicts).
 * launch_bounds(512,1) = 256-VGPR cap (spill lessons r2-4). */
__global__ __launch_bounds__(512, 1) void pairwise_kernel(
    const float* __restrict__ points, const float* __restrict__ nuv,
    const float* __restrict__ A2, const float* __restrict__ B2,
    const float* __restrict__ ipack,
    const float* __restrict__ traw, const float* __restrict__ partials,
    const float* __restrict__ gw, const float* __restrict__ gb,
    float* __restrict__ fout)
{
    const int t     = threadIdx.x;
    const int lane  = t & 63;
    const int h     = lane & 31;          /* B/D column; local j within tile */
    const bool kh   = (lane >> 5) != 0;
    const int khalf = lane >> 5;
    const int ibase = blockIdx.y * ICH;
    const int jt0   = blockIdx.x * 512 + (t >> 6) * 64;   /* tile A base */

    __shared__ float sacc[ICH][32];       /* 1 KB tile accumulator */
    if (t < ICH * 32) ((float*)sacc)[t] = 0.f;
    __syncthreads();

    /* ---- per-lane j-side for both tiles (loaded once) ---- */
    const int jA = jt0 + h, jB = jt0 + 32 + h;
    const float pjxA = points[jA * 3 + 0] * PSCALE;
    const float pjyA = points[jA * 3 + 1] * PSCALE;
    const float pjzA = points[jA * 3 + 2] * PSCALE;
    const float njxA = nuv[jA * 9 + 0], njyA = nuv[jA * 9 + 1], njzA = nuv[jA * 9 + 2];
    const float qjA  = fmaf(pjxA, pjxA, fmaf(pjyA, pjyA, pjzA * pjzA));
    const float pjxB = points[jB * 3 + 0] * PSCALE;
    const float pjyB = points[jB * 3 + 1] * PSCALE;
    const float pjzB = points[jB * 3 + 2] * PSCALE;
    const float njxB = nuv[jB * 9 + 0], njyB = nuv[jB * 9 + 1], njzB = nuv[jB * 9 + 2];
    const float qjB  = fmaf(pjxB, pjxB, fmaf(pjyB, pjyB, pjzB * pjzB));

    /* own-half j coords for the single u-chain (prologue cndmasks, one-time) */
    const float pjxO = kh ? pjxB : pjxA;
    const float pjyO = kh ? pjyB : pjyA;
    const float pjzO = kh ? pjzB : pjzA;

    /* ---- B fragments: tile A = r10 layout, tile B = khalf-mirrored ---- */
    bf16x8 bM0, bM1;
    {
        const __bf16 b2h = (__bf16)B2[h];
        const __bf16 zb  = (__bf16)0.f;
#pragma unroll
        for (int e = 0; e < 8; ++e) {
            const __bf16 a2v   = (__bf16)A2[h * 8 + e];
            const __bf16 wslot = (e == 0) ? b2h : zb;
            bM0[e] = kh ? wslot : a2v;    /* A2 at k0-7, B2 bias at k8 */
            bM1[e] = kh ? a2v : wslot;    /* B2 bias at k0, A2 at k8-15 */
        }
    }

    /* ---- GroupNorm-on-the-fly f registers, 16 per tile ---- */
    const int g4 = h >> 3;
    float s = 0.f, q = 0.f;
#pragma unroll
    for (int b = 0; b < 32; ++b) {
        s += partials[g4 * 32 + b];
        q += partials[128 + g4 * 32 + b];
    }
    const float inv = 1.f / (8.f * NPTS);
    const float mu = s * inv;
    const float rs = rsqrtf(q * inv - mu * mu + EPSV);
    const float alpha = rs * gw[h];
    const float gamma = fmaf(-mu, alpha, gb[h]);
    float fregA[16], fregB[16];
#pragma unroll
    for (int r = 0; r < 16; ++r) {
        const int jr = (r & 3) + 8 * (r >> 2) + 4 * khalf;  /* D row for reg r */
        fregA[r] = fmaf(traw[(jt0 + jr) * HDIM + h],      alpha, gamma);
        fregB[r] = fmaf(traw[(jt0 + 32 + jr) * HDIM + h], alpha, gamma);
    }

    f32x16 czero;
#pragma unroll
    for (int e = 0; e < 16; ++e) czero[e] = 0.f;

    float accv[ICH];
#pragma unroll
    for (int il = 0; il < ICH; ++il) accv[il] = 0.f;

/* load one i's pack into named register buffers (wave-uniform -> s_load) */
#define LOADI(M, G8, G9, il) do {                                             \
        const float4* ip4 = (const float4*)(ipack + (ibase + (il)) * IPK);    \
        M[0] = ip4[0]; M[1] = ip4[1]; M[2] = ip4[2]; M[3] = ip4[3];           \
        M[4] = ip4[4]; M[5] = ip4[5]; M[6] = ip4[6]; M[7] = ip4[7];           \
        G8 = ip4[8]; G9 = ip4[9];                                             \
    } while (0)

/* one i against BOTH 32-j tiles. Windows for both tiles are computed
 * per-lane (cheap); the u-chain runs ONCE per lane on its own half's pj. */
#define BODY2(M, G8, G9, il) do {                                             \
        const float sqA = fmaf(G8.x, pjxA, fmaf(G8.y, pjyA,                   \
                          fmaf(G8.z, pjzA, G8.w))) + qjA;                     \
        const float sqB = fmaf(G8.x, pjxB, fmaf(G8.y, pjyB,                   \
                          fmaf(G8.z, pjzB, G8.w))) + qjB;                     \
        const float dtA = fmaf(G9.x, njxA, fmaf(G9.y, njyA, G9.z * njzA));    \
        const float dtB = fmaf(G9.x, njxB, fmaf(G9.y, njyB, G9.z * njzB));    \
        const float ttA = 2.f - dtA, ttB = 2.f - dtB;                         \
        const float wvA = __expf(-sqA * ttA * ttA);                           \
        const float wvB = __expf(-sqB * ttB * ttB);                           \
        const float wvO = kh ? wvB : wvA;                                     \
        float u[8];                                                           \
        _Pragma("unroll")                                                     \
        for (int c = 0; c < 8; ++c) {                                         \
            u[c] = wvO * fmaxf(fmaf(M[c].x, pjxO, fmaf(M[c].y, pjyO,          \
                               fmaf(M[c].z, pjzO, M[c].w))), 0.f);            \
        }                                                                     \
        const __bf16 wbA = (__bf16)wvA;                                       \
        const __bf16 wbB = (__bf16)wvB;                                       \
        const __bf16 zb  = (__bf16)0.f;                                       \
        bf16x8 afA, afB;                                                      \
        _Pragma("unroll")                                                     \
        for (int e = 0; e < 8; ++e) {                                         \
            const __bf16 ub = (__bf16)u[e];                                   \
            afA[e] = kh ? ((e == 0) ? wbA : zb) : ub;                         \
            afB[e] = kh ? ub : ((e == 0) ? wbB : zb);                         \
        }                                                                     \
        const f32x16 dA = __builtin_amdgcn_mfma_f32_32x32x16_bf16(            \
            afA, bM0, czero, 0, 0, 0);                                        \
        const f32x16 dB = __builtin_amdgcn_mfma_f32_32x32x16_bf16(            \
            afB, bM1, czero, 0, 0, 0);                                        \
        float a0 = 0.f, a1 = 0.f, b0 = 0.f, b1 = 0.f;                         \
        _Pragma("unroll")                                                     \
        for (int r = 0; r < 16; r += 2) {                                     \
            a0 = fmaf(fmaxf(dA[r],     0.f), fregA[r],     a0);               \
            a1 = fmaf(fmaxf(dA[r + 1], 0.f), fregA[r + 1], a1);               \
            b0 = fmaf(fmaxf(dB[r],     0.f), fregB[r],     b0);               \
            b1 = fmaf(fmaxf(dB[r + 1], 0.f), fregB[r + 1], b1);               \
        }                                                                     \
        accv[il] = (a0 + a1) + (b0 + b1);                                     \
    } while (0)

    /* ---- 2-deep pipelined i-loop; no fences: let 4 MFMA chains overlap ---- */
    float4 MA[8], MB[8], GA8, GA9, GB8, GB9;
    LOADI(MA, GA8, GA9, 0);
#pragma unroll 1
    for (int ii = 0; ii < ICH; ii += 2) {
        LOADI(MB, GB8, GB9, ii + 1);
        BODY2(MA, GA8, GA9, ii);
        if (ii + 2 < ICH) LOADI(MA, GA8, GA9, ii + 2);
        BODY2(MB, GB8, GB9, ii + 1);
    }
#undef LOADI
#undef BODY2

    /* ---- block-level reduction via LDS atomics (outside the hot loop) ---- */
#pragma unroll
    for (int il = 0; il < ICH; ++il)
        atomicAdd(&sacc[il][h], accv[il]);
    __syncthreads();

    /* ---- flush tile to global (ICH*32 = 256 cells) ---- */
    if (t < ICH * 32) {
        const int il0 = t >> 5, h0 = t & 31;
        atomicAdd(&fout[(ibase + il0) * HDIM + h0], sacc[il0][h0]);
    }
}

extern "C" void kernel_launch(void* const* d_in, const int* in_sizes, int n_in,
                              void* d_out, int out_size, void* d_ws, size_t ws_size,
                              hipStream_t stream)
{
    const float* points   = (const float*)d_in[0];
    const float* nuv      = (const float*)d_in[1];
    const float* features = (const float*)d_in[2];
    const float* W_in1    = (const float*)d_in[3];
    const float* b_in1    = (const float*)d_in[4];
    const float* W_in2    = (const float*)d_in[5];
    const float* b_in2    = (const float*)d_in[6];
    const float* g_in_w   = (const float*)d_in[7];
    const float* g_in_b   = (const float*)d_in[8];
    const float* A1       = (const float*)d_in[9];
    const float* A2       = (const float*)d_in[10];
    const float* W_out1   = (const float*)d_in[11];
    const float* b_out1   = (const float*)d_in[12];
    const float* W_out2   = (const float*)d_in[13];
    const float* b_out2   = (const float*)d_in[14];
    const float* g_out_w  = (const float*)d_in[15];
    const float* g_out_b  = (const float*)d_in[16];
    const float* B1       = (const float*)d_in[17];
    const float* B2       = (const float*)d_in[18];

    float* ws    = (float*)d_ws;
    float* t2a   = ws;               /* N*H raw net_in output */
    float* t2b   = ws + 65536;       /* N*H raw net_out output */
    float* fout  = ws + 131072;      /* N*H pairwise accumulator */
    float* ipack = ws + 196608;      /* N*IPK = 98304 */
    float* part1 = ws + 294912;      /* 256 floats */
    float* part2 = ws + 295168;      /* 256 floats */
    float* out   = (float*)d_out;

    /* net_in (+stats partials, +zero fout, +ipack) */
    net2_kernel<IDIM><<<dim3(NPTS / 64), dim3(64), 0, stream>>>(
        features, W_in1, b_in1, W_in2, b_in2, t2a, part1, fout,
        points, nuv, A1, B1, ipack);

    /* all-pairs interaction (GroupNorm of f applied on the fly) */
    pairwise_kernel<<<dim3(NPTS / 512, NPTS / ICH), dim3(512), 0, stream>>>(
        points, nuv, A2, B2, ipack, t2a, part1, g_in_w, g_in_b, fout);

    /* net_out (+stats partials), then final normalize -> out */
    net2_kernel<HDIM><<<dim3(NPTS / 64), dim3(64), 0, stream>>>(
        fout, W_out1, b_out1, W_out2, b_out2, t2b, part2, nullptr,
        nullptr, nullptr, nullptr, nullptr, nullptr);
    gn_apply_kernel<<<dim3(NPTS * HDIM / 256), dim3(256), 0, stream>>>(
        t2b, part2, g_out_w, g_out_b, out);
}